// Round 2
// baseline (51114.368 us; speedup 1.0000x reference)
//
#include <hip/hip_runtime.h>

#define T_STEPS 32768
#define OUT_BASE 9830400  // 32768*300

typedef _Float16 h2 __attribute__((ext_vector_type(2)));

__device__ __forceinline__ float fdot2(h2 a, h2 b, float c) {
#if __has_builtin(__builtin_amdgcn_fdot2)
    return __builtin_amdgcn_fdot2(a, b, c, false);
#else
    return c + (float)a.x * (float)b.x + (float)a.y * (float)b.y;
#endif
}

__device__ __forceinline__ float sigf(float x) { return 1.f / (1.f + __expf(-x)); }

__device__ __forceinline__ float tanh_f(float x) {
    float a = fabsf(x);
    float e = __expf(-2.f * a);
    float t = (1.f - e) / (1.f + e);
    return x < 0.f ? -t : t;
}

// ---------------- A0: Wc = W_ih_l0 @ W_inp  [400x300]; bc = W_ih_l0@b_inp + b_ih0 + b_hh0 ----------------
__global__ void k_precomp(const float* __restrict__ W_inp, const float* __restrict__ b_inp,
                          const float* __restrict__ W_ih0, const float* __restrict__ b_ih0,
                          const float* __restrict__ b_hh0,
                          float* __restrict__ Wc, float* __restrict__ bc) {
    int idx = blockIdx.x * 256 + threadIdx.x;
    if (idx < 120000) {
        int r = idx / 300, d = idx % 300;
        float acc = 0.f;
        for (int h = 0; h < 100; h++) acc += W_ih0[r * 100 + h] * W_inp[h * 300 + d];
        Wc[idx] = acc;
    } else if (idx < 120400) {
        int r = idx - 120000;
        float acc = b_ih0[r] + b_hh0[r];
        for (int h = 0; h < 100; h++) acc += W_ih0[r * 100 + h] * b_inp[h];
        bc[r] = acc;
    }
}

// ---------------- A1: x0p[t][r] = inputs[t] . Wc[r] + bc[r], stored f16 ----------------
__global__ __launch_bounds__(512) void k_xproj(const float* __restrict__ inp,
                                               const float* __restrict__ Wc,
                                               const float* __restrict__ bc,
                                               _Float16* __restrict__ x0p) {
    __shared__ float xs[32 * 300];
    int t0 = blockIdx.x * 32;
    for (int idx = threadIdx.x; idx < 9600; idx += 512) xs[idx] = inp[(size_t)t0 * 300 + idx];
    __syncthreads();
    int j = threadIdx.x;
    if (j < 400) {
        float acc[32];
#pragma unroll
        for (int i = 0; i < 32; i++) acc[i] = 0.f;
        const float4* w4 = (const float4*)(Wc + j * 300);
        const float4* x4 = (const float4*)xs;
        for (int d4 = 0; d4 < 75; d4++) {
            float4 w = w4[d4];
#pragma unroll
            for (int ti = 0; ti < 32; ti++) {
                float4 x = x4[ti * 75 + d4];
                acc[ti] += w.x * x.x + w.y * x.y + w.z * x.z + w.w * x.w;
            }
        }
        float bb = bc[j];
#pragma unroll
        for (int ti = 0; ti < 32; ti++)
            x0p[(size_t)(t0 + ti) * 400 + j] = (_Float16)(acc[ti] + bb);
    }
}

// ---------------- Scan: single block, layers software-pipelined (layer1 lags 1 tick) ----------------
// Tick t: MV phase computes gates0(t) AND gates1(t-1) (both need only state written at tick t-1).
// Update phase: threads 0-99 -> h0(t),c0(t); threads 100-199 -> h1(t-1),c1(t-1). 2 barriers/tick.
// __launch_bounds__(512,2): VGPR cap 256 so the 150 packed-f16 weight regs stay in arch VGPRs (no AGPR spill).
__global__ __launch_bounds__(512, 2) void k_scan(const _Float16* __restrict__ x0p,
                                                 const float* __restrict__ Whh0,
                                                 const float* __restrict__ Wih1,
                                                 const float* __restrict__ Whh1,
                                                 const float* __restrict__ bih1,
                                                 const float* __restrict__ bhh1,
                                                 float* __restrict__ h1s,
                                                 float* __restrict__ outTail) {
    __shared__ __align__(16) unsigned int hcat[104];  // packed f16 pairs: [0..49]=h0, [50..99]=h1
    __shared__ float gates[800];                      // [0..399]=gates0(t), [400..799]=gates1(t-1)
    const int j = threadIdx.x;

    h2 w0[50];   // W_hh_l0 row j (packed f16)
    h2 w1[100];  // [W_ih_l1 row j | W_hh_l1 row j]
    float b1c = 0.f, xn = 0.f;
    if (j < 400) {
        const float2* p0 = (const float2*)(Whh0 + j * 100);
#pragma unroll
        for (int k = 0; k < 50; k++) { float2 v = p0[k]; h2 q; q.x = (_Float16)v.x; q.y = (_Float16)v.y; w0[k] = q; }
        const float2* p1 = (const float2*)(Wih1 + j * 100);
#pragma unroll
        for (int k = 0; k < 50; k++) { float2 v = p1[k]; h2 q; q.x = (_Float16)v.x; q.y = (_Float16)v.y; w1[k] = q; }
        const float2* p2 = (const float2*)(Whh1 + j * 100);
#pragma unroll
        for (int k = 0; k < 50; k++) { float2 v = p2[k]; h2 q; q.x = (_Float16)v.x; q.y = (_Float16)v.y; w1[50 + k] = q; }
        b1c = bih1[j] + bhh1[j];
        xn = (float)x0p[j];  // prefetch t=0
    }
    if (j < 104) hcat[j] = 0u;
    float c0 = 0.f, c1 = 0.f, h0v = 0.f, h1v = 0.f;
    __syncthreads();

    for (int t = 0; t <= T_STEPS; t++) {
        float xc = xn;
        if (j < 400) {
            if (t < T_STEPS) {
                int tn = (t < T_STEPS - 1) ? t + 1 : t;
                xn = (float)x0p[(size_t)tn * 400 + j];  // prefetch next tick's x-projection
            }
            const float4* h4 = (const float4*)hcat;
            float acc0 = xc;   // gates0(t) row j   (garbage at t==T_STEPS; unused then)
            float acc1 = b1c;  // gates1(t-1) row j (b1c only at t==0; unused then)
#pragma unroll
            for (int c = 0; c < 12; c++) {  // h0 pairs 0..47 feed BOTH MV0 and MV1
                float4 v = h4[c];
                h2 hx = __builtin_bit_cast(h2, v.x), hy = __builtin_bit_cast(h2, v.y);
                h2 hz = __builtin_bit_cast(h2, v.z), hw = __builtin_bit_cast(h2, v.w);
                acc0 = fdot2(w0[4 * c + 0], hx, acc0);
                acc1 = fdot2(w1[4 * c + 0], hx, acc1);
                acc0 = fdot2(w0[4 * c + 1], hy, acc0);
                acc1 = fdot2(w1[4 * c + 1], hy, acc1);
                acc0 = fdot2(w0[4 * c + 2], hz, acc0);
                acc1 = fdot2(w1[4 * c + 2], hz, acc1);
                acc0 = fdot2(w0[4 * c + 3], hw, acc0);
                acc1 = fdot2(w1[4 * c + 3], hw, acc1);
            }
            {  // c=12: h0 pairs 48,49 + h1 pairs 0,1
                float4 v = h4[12];
                h2 hx = __builtin_bit_cast(h2, v.x), hy = __builtin_bit_cast(h2, v.y);
                h2 hz = __builtin_bit_cast(h2, v.z), hw = __builtin_bit_cast(h2, v.w);
                acc0 = fdot2(w0[48], hx, acc0);
                acc1 = fdot2(w1[48], hx, acc1);
                acc0 = fdot2(w0[49], hy, acc0);
                acc1 = fdot2(w1[49], hy, acc1);
                acc1 = fdot2(w1[50], hz, acc1);
                acc1 = fdot2(w1[51], hw, acc1);
            }
#pragma unroll
            for (int c = 13; c < 25; c++) {  // h1 pairs 2..49
                float4 v = h4[c];
                acc1 = fdot2(w1[4 * c + 0], __builtin_bit_cast(h2, v.x), acc1);
                acc1 = fdot2(w1[4 * c + 1], __builtin_bit_cast(h2, v.y), acc1);
                acc1 = fdot2(w1[4 * c + 2], __builtin_bit_cast(h2, v.z), acc1);
                acc1 = fdot2(w1[4 * c + 3], __builtin_bit_cast(h2, v.w), acc1);
            }
            gates[j] = acc0;
            gates[400 + j] = acc1;
        }
        __syncthreads();
        if (j < 100) {  // layer-0 state update for step t
            if (t < T_STEPS) {
                float gi = gates[j], gf = gates[j + 100], gg = gates[j + 200], go = gates[j + 300];
                c0 = sigf(gf) * c0 + sigf(gi) * tanh_f(gg);
                h0v = sigf(go) * tanh_f(c0);
                float hp = __shfl_xor(h0v, 1);
                if (!(j & 1)) { h2 q; q.x = (_Float16)h0v; q.y = (_Float16)hp; hcat[j >> 1] = __builtin_bit_cast(unsigned int, q); }
                if (t == T_STEPS - 1) { outTail[j] = h0v; outTail[200 + j] = c0; }
            }
        } else if (j < 200) {  // layer-1 state update for step t-1
            if (t >= 1) {
                int i = j - 100;
                float gi = gates[400 + i], gf = gates[500 + i], gg = gates[600 + i], go = gates[700 + i];
                c1 = sigf(gf) * c1 + sigf(gi) * tanh_f(gg);
                h1v = sigf(go) * tanh_f(c1);
                h1s[(size_t)(t - 1) * 100 + i] = h1v;
                float hp = __shfl_xor(h1v, 1);
                if (!(i & 1)) { h2 q; q.x = (_Float16)h1v; q.y = (_Float16)hp; hcat[50 + (i >> 1)] = __builtin_bit_cast(unsigned int, q); }
                if (t == T_STEPS) { outTail[100 + i] = h1v; outTail[300 + i] = c1; }
            }
        }
        __syncthreads();
    }
}

// ---------------- C: outputs[t][d] = h1s[t] . W_out[d] + b_out[d] ----------------
__global__ __launch_bounds__(320) void k_out(const float* __restrict__ h1s,
                                             const float* __restrict__ Wout,
                                             const float* __restrict__ bout,
                                             float* __restrict__ out) {
    __shared__ float hs[32 * 100];
    int t0 = blockIdx.x * 32;
    for (int idx = threadIdx.x; idx < 3200; idx += 320) hs[idx] = h1s[(size_t)t0 * 100 + idx];
    __syncthreads();
    int d = threadIdx.x;
    if (d < 300) {
        float acc[32];
#pragma unroll
        for (int i = 0; i < 32; i++) acc[i] = 0.f;
        const float4* w4 = (const float4*)(Wout + d * 100);
        const float4* h4 = (const float4*)hs;
        for (int j4 = 0; j4 < 25; j4++) {
            float4 w = w4[j4];
#pragma unroll
            for (int ti = 0; ti < 32; ti++) {
                float4 h = h4[ti * 25 + j4];
                acc[ti] += w.x * h.x + w.y * h.y + w.z * h.z + w.w * h.w;
            }
        }
        float bb = bout[d];
#pragma unroll
        for (int ti = 0; ti < 32; ti++) out[(size_t)(t0 + ti) * 300 + d] = acc[ti] + bb;
    }
}

extern "C" void kernel_launch(void* const* d_in, const int* in_sizes, int n_in,
                              void* d_out, int out_size, void* d_ws, size_t ws_size,
                              hipStream_t stream) {
    const float* inputs = (const float*)d_in[0];
    const float* W_inp  = (const float*)d_in[1];
    const float* b_inp  = (const float*)d_in[2];
    const float* W_ih0  = (const float*)d_in[3];
    const float* W_hh0  = (const float*)d_in[4];
    const float* b_ih0  = (const float*)d_in[5];
    const float* b_hh0  = (const float*)d_in[6];
    const float* W_ih1  = (const float*)d_in[7];
    const float* W_hh1  = (const float*)d_in[8];
    const float* b_ih1  = (const float*)d_in[9];
    const float* b_hh1  = (const float*)d_in[10];
    const float* W_out  = (const float*)d_in[11];
    const float* b_out  = (const float*)d_in[12];
    float* out = (float*)d_out;

    char* ws = (char*)d_ws;
    _Float16* x0p = (_Float16*)ws;                         // 32768*400*2 = 26,214,400 B
    float* h1s = (float*)(ws + 26214400);                  // 32768*100*4 = 13,107,200 B
    float* Wc  = (float*)(ws + 26214400 + 13107200);       // 400*300*4   =    480,000 B
    float* bc  = Wc + 120000;                              // 400*4 B

    k_precomp<<<471, 256, 0, stream>>>(W_inp, b_inp, W_ih0, b_ih0, b_hh0, Wc, bc);
    k_xproj<<<1024, 512, 0, stream>>>(inputs, Wc, bc, x0p);
    k_scan<<<1, 512, 0, stream>>>(x0p, W_hh0, W_ih1, W_hh1, b_ih1, b_hh1, h1s, out + OUT_BASE);
    k_out<<<1024, 320, 0, stream>>>(h1s, W_out, b_out, out);
}

// Round 3
// 39437.540 us; speedup vs baseline: 1.2961x; 1.2961x over previous
//
#include <hip/hip_runtime.h>

#define T_STEPS 32768
#define OUT_BASE 9830400  // 32768*300

typedef _Float16 h2 __attribute__((ext_vector_type(2)));

__device__ __forceinline__ float fdot2(h2 a, h2 b, float c) {
#if __has_builtin(__builtin_amdgcn_fdot2)
    return __builtin_amdgcn_fdot2(a, b, c, false);
#else
    return c + (float)a.x * (float)b.x + (float)a.y * (float)b.y;
#endif
}

__device__ __forceinline__ float sigf(float x) { return 1.f / (1.f + __expf(-x)); }

__device__ __forceinline__ float tanh_f(float x) {
    float a = fabsf(x);
    float e = __expf(-2.f * a);
    float t = (1.f - e) / (1.f + e);
    return x < 0.f ? -t : t;
}

// Barrier that drains ONLY LDS (lgkmcnt). __syncthreads() would emit
// s_waitcnt vmcnt(0) before s_barrier, serializing the x0p prefetch /
// h1s store latency into every tick. Our globals have no cross-thread
// dependency inside this kernel, so LDS-only is sufficient.
__device__ __forceinline__ void bar_lds() {
    asm volatile("s_waitcnt lgkmcnt(0)\n\ts_barrier" ::: "memory");
}

// ---------------- A0: Wc = W_ih_l0 @ W_inp  [400x300]; bc = W_ih_l0@b_inp + b_ih0 + b_hh0 ----------------
__global__ void k_precomp(const float* __restrict__ W_inp, const float* __restrict__ b_inp,
                          const float* __restrict__ W_ih0, const float* __restrict__ b_ih0,
                          const float* __restrict__ b_hh0,
                          float* __restrict__ Wc, float* __restrict__ bc) {
    int idx = blockIdx.x * 256 + threadIdx.x;
    if (idx < 120000) {
        int r = idx / 300, d = idx % 300;
        float acc = 0.f;
        for (int h = 0; h < 100; h++) acc += W_ih0[r * 100 + h] * W_inp[h * 300 + d];
        Wc[idx] = acc;
    } else if (idx < 120400) {
        int r = idx - 120000;
        float acc = b_ih0[r] + b_hh0[r];
        for (int h = 0; h < 100; h++) acc += W_ih0[r * 100 + h] * b_inp[h];
        bc[r] = acc;
    }
}

// ---------------- A1: x0p[t][r] = inputs[t] . Wc[r] + bc[r], stored f16 ----------------
__global__ __launch_bounds__(512) void k_xproj(const float* __restrict__ inp,
                                               const float* __restrict__ Wc,
                                               const float* __restrict__ bc,
                                               _Float16* __restrict__ x0p) {
    __shared__ float xs[32 * 300];
    int t0 = blockIdx.x * 32;
    for (int idx = threadIdx.x; idx < 9600; idx += 512) xs[idx] = inp[(size_t)t0 * 300 + idx];
    __syncthreads();
    int j = threadIdx.x;
    if (j < 400) {
        float acc[32];
#pragma unroll
        for (int i = 0; i < 32; i++) acc[i] = 0.f;
        const float4* w4 = (const float4*)(Wc + j * 300);
        const float4* x4 = (const float4*)xs;
        for (int d4 = 0; d4 < 75; d4++) {
            float4 w = w4[d4];
#pragma unroll
            for (int ti = 0; ti < 32; ti++) {
                float4 x = x4[ti * 75 + d4];
                acc[ti] += w.x * x.x + w.y * x.y + w.z * x.z + w.w * x.w;
            }
        }
        float bb = bc[j];
#pragma unroll
        for (int ti = 0; ti < 32; ti++)
            x0p[(size_t)(t0 + ti) * 400 + j] = (_Float16)(acc[ti] + bb);
    }
}

// One pipelined tick: MV phase computes gates0(t) and gates1(t-1); update phase
// applies layer-0 step t (threads 0-99) and layer-1 step t-1 (threads 256-355,
// separate waves to avoid divergence). XREG_ holds x0p(t) and is refilled for TNEXT_.
#define TICK(T_, XREG_, TNEXT_) do {                                                         \
    float xc_ = XREG_;                                                                       \
    if (j < 400) {                                                                           \
        int tn_ = (TNEXT_) < T_STEPS ? (TNEXT_) : T_STEPS - 1;                               \
        XREG_ = (float)x0p[(size_t)tn_ * 400 + j];                                           \
        const float4* h4_ = (const float4*)hcat;                                             \
        float acc0_ = xc_, acc1_ = b1c;                                                      \
        _Pragma("unroll")                                                                    \
        for (int c_ = 0; c_ < 12; c_++) {                                                    \
            float4 v_ = h4_[c_];                                                             \
            h2 hx_ = __builtin_bit_cast(h2, v_.x), hy_ = __builtin_bit_cast(h2, v_.y);       \
            h2 hz_ = __builtin_bit_cast(h2, v_.z), hw_ = __builtin_bit_cast(h2, v_.w);       \
            acc0_ = fdot2(w0[4 * c_ + 0], hx_, acc0_);                                       \
            acc1_ = fdot2(w1[4 * c_ + 0], hx_, acc1_);                                       \
            acc0_ = fdot2(w0[4 * c_ + 1], hy_, acc0_);                                       \
            acc1_ = fdot2(w1[4 * c_ + 1], hy_, acc1_);                                       \
            acc0_ = fdot2(w0[4 * c_ + 2], hz_, acc0_);                                       \
            acc1_ = fdot2(w1[4 * c_ + 2], hz_, acc1_);                                       \
            acc0_ = fdot2(w0[4 * c_ + 3], hw_, acc0_);                                       \
            acc1_ = fdot2(w1[4 * c_ + 3], hw_, acc1_);                                       \
        }                                                                                    \
        {                                                                                    \
            float4 v_ = h4_[12];                                                             \
            h2 hx_ = __builtin_bit_cast(h2, v_.x), hy_ = __builtin_bit_cast(h2, v_.y);       \
            h2 hz_ = __builtin_bit_cast(h2, v_.z), hw_ = __builtin_bit_cast(h2, v_.w);       \
            acc0_ = fdot2(w0[48], hx_, acc0_);                                               \
            acc1_ = fdot2(w1[48], hx_, acc1_);                                               \
            acc0_ = fdot2(w0[49], hy_, acc0_);                                               \
            acc1_ = fdot2(w1[49], hy_, acc1_);                                               \
            acc1_ = fdot2(w1[50], hz_, acc1_);                                               \
            acc1_ = fdot2(w1[51], hw_, acc1_);                                               \
        }                                                                                    \
        _Pragma("unroll")                                                                    \
        for (int c_ = 13; c_ < 25; c_++) {                                                   \
            float4 v_ = h4_[c_];                                                             \
            acc1_ = fdot2(w1[4 * c_ + 0], __builtin_bit_cast(h2, v_.x), acc1_);              \
            acc1_ = fdot2(w1[4 * c_ + 1], __builtin_bit_cast(h2, v_.y), acc1_);              \
            acc1_ = fdot2(w1[4 * c_ + 2], __builtin_bit_cast(h2, v_.z), acc1_);              \
            acc1_ = fdot2(w1[4 * c_ + 3], __builtin_bit_cast(h2, v_.w), acc1_);              \
        }                                                                                    \
        gates[j] = acc0_;                                                                    \
        gates[400 + j] = acc1_;                                                              \
    }                                                                                        \
    bar_lds();                                                                               \
    if (j < 100) {                                                                           \
        float gi_ = gates[j], gf_ = gates[j + 100], gg_ = gates[j + 200], go_ = gates[j + 300]; \
        c0 = sigf(gf_) * c0 + sigf(gi_) * tanh_f(gg_);                                       \
        h0v = sigf(go_) * tanh_f(c0);                                                        \
        float hp_ = __shfl_xor(h0v, 1);                                                      \
        if (!(j & 1)) { h2 q_; q_.x = (_Float16)h0v; q_.y = (_Float16)hp_;                   \
                        hcat[j >> 1] = __builtin_bit_cast(unsigned int, q_); }               \
        if ((T_) == T_STEPS - 1) { outTail[j] = h0v; outTail[200 + j] = c0; }                \
    } else if (j >= 256 && j < 356) {                                                        \
        if ((T_) >= 1) {                                                                     \
            int i_ = j - 256;                                                                \
            float gi_ = gates[400 + i_], gf_ = gates[500 + i_];                              \
            float gg_ = gates[600 + i_], go_ = gates[700 + i_];                              \
            c1 = sigf(gf_) * c1 + sigf(gi_) * tanh_f(gg_);                                   \
            h1v = sigf(go_) * tanh_f(c1);                                                    \
            h1s[(size_t)((T_) - 1) * 100 + i_] = h1v;                                        \
            float hp_ = __shfl_xor(h1v, 1);                                                  \
            if (!(i_ & 1)) { h2 q_; q_.x = (_Float16)h1v; q_.y = (_Float16)hp_;              \
                             hcat[50 + (i_ >> 1)] = __builtin_bit_cast(unsigned int, q_); }  \
        }                                                                                    \
    }                                                                                        \
    bar_lds();                                                                               \
} while (0)

// ---------------- Scan: single block, layers software-pipelined (layer1 lags 1 tick) ----------------
// amdgpu_waves_per_eu(2,2): pin exactly 2 waves/SIMD -> 256-VGPR budget so the
// 150 packed-f16 weight regs stay in arch VGPRs (round-2's launch_bounds(512,2)
// left VGPR_Count=128 with AGPR copies in the hot loop).
__global__ __launch_bounds__(512) __attribute__((amdgpu_waves_per_eu(2, 2)))
void k_scan(const _Float16* __restrict__ x0p,
            const float* __restrict__ Whh0,
            const float* __restrict__ Wih1,
            const float* __restrict__ Whh1,
            const float* __restrict__ bih1,
            const float* __restrict__ bhh1,
            float* __restrict__ h1s,
            float* __restrict__ outTail) {
    __shared__ __align__(16) unsigned int hcat[104];  // packed f16 pairs: [0..49]=h0, [50..99]=h1
    __shared__ float gates[800];                      // [0..399]=gates0(t), [400..799]=gates1(t-1)
    const int j = threadIdx.x;

    h2 w0[50];   // W_hh_l0 row j (packed f16)
    h2 w1[100];  // [W_ih_l1 row j | W_hh_l1 row j]
    float b1c = 0.f, xa = 0.f, xb = 0.f;
    if (j < 400) {
        const float2* p0 = (const float2*)(Whh0 + j * 100);
#pragma unroll
        for (int k = 0; k < 50; k++) { float2 v = p0[k]; h2 q; q.x = (_Float16)v.x; q.y = (_Float16)v.y; w0[k] = q; }
        const float2* p1 = (const float2*)(Wih1 + j * 100);
#pragma unroll
        for (int k = 0; k < 50; k++) { float2 v = p1[k]; h2 q; q.x = (_Float16)v.x; q.y = (_Float16)v.y; w1[k] = q; }
        const float2* p2 = (const float2*)(Whh1 + j * 100);
#pragma unroll
        for (int k = 0; k < 50; k++) { float2 v = p2[k]; h2 q; q.x = (_Float16)v.x; q.y = (_Float16)v.y; w1[50 + k] = q; }
        b1c = bih1[j] + bhh1[j];
        xa = (float)x0p[j];        // x(0)
        xb = (float)x0p[400 + j];  // x(1)
    }
    if (j < 104) hcat[j] = 0u;
    float c0 = 0.f, c1 = 0.f, h0v = 0.f, h1v = 0.f;
    __syncthreads();

    for (int t = 0; t < T_STEPS; t += 2) {
        TICK(t, xa, t + 2);      // distance-2 prefetch: refill xa for tick t+2
        TICK(t + 1, xb, t + 3);  // refill xb for tick t+3
    }

    // Drain tick (t == T_STEPS): gates1 for step T-1, then final layer-1 update.
    if (j < 400) {
        const float4* h4 = (const float4*)hcat;
        float acc1 = b1c;
#pragma unroll
        for (int c = 0; c < 25; c++) {
            float4 v = h4[c];
            acc1 = fdot2(w1[4 * c + 0], __builtin_bit_cast(h2, v.x), acc1);
            acc1 = fdot2(w1[4 * c + 1], __builtin_bit_cast(h2, v.y), acc1);
            acc1 = fdot2(w1[4 * c + 2], __builtin_bit_cast(h2, v.z), acc1);
            acc1 = fdot2(w1[4 * c + 3], __builtin_bit_cast(h2, v.w), acc1);
        }
        gates[400 + j] = acc1;
    }
    bar_lds();
    if (j >= 256 && j < 356) {
        int i = j - 256;
        float gi = gates[400 + i], gf = gates[500 + i], gg = gates[600 + i], go = gates[700 + i];
        c1 = sigf(gf) * c1 + sigf(gi) * tanh_f(gg);
        h1v = sigf(go) * tanh_f(c1);
        h1s[(size_t)(T_STEPS - 1) * 100 + i] = h1v;
        outTail[100 + i] = h1v;
        outTail[300 + i] = c1;
    }
}

// ---------------- C: outputs[t][d] = h1s[t] . W_out[d] + b_out[d] ----------------
__global__ __launch_bounds__(320) void k_out(const float* __restrict__ h1s,
                                             const float* __restrict__ Wout,
                                             const float* __restrict__ bout,
                                             float* __restrict__ out) {
    __shared__ float hs[32 * 100];
    int t0 = blockIdx.x * 32;
    for (int idx = threadIdx.x; idx < 3200; idx += 320) hs[idx] = h1s[(size_t)t0 * 100 + idx];
    __syncthreads();
    int d = threadIdx.x;
    if (d < 300) {
        float acc[32];
#pragma unroll
        for (int i = 0; i < 32; i++) acc[i] = 0.f;
        const float4* w4 = (const float4*)(Wout + d * 100);
        const float4* h4 = (const float4*)hs;
        for (int j4 = 0; j4 < 25; j4++) {
            float4 w = w4[j4];
#pragma unroll
            for (int ti = 0; ti < 32; ti++) {
                float4 h = h4[ti * 25 + j4];
                acc[ti] += w.x * h.x + w.y * h.y + w.z * h.z + w.w * h.w;
            }
        }
        float bb = bout[d];
#pragma unroll
        for (int ti = 0; ti < 32; ti++) out[(size_t)(t0 + ti) * 300 + d] = acc[ti] + bb;
    }
}

extern "C" void kernel_launch(void* const* d_in, const int* in_sizes, int n_in,
                              void* d_out, int out_size, void* d_ws, size_t ws_size,
                              hipStream_t stream) {
    const float* inputs = (const float*)d_in[0];
    const float* W_inp  = (const float*)d_in[1];
    const float* b_inp  = (const float*)d_in[2];
    const float* W_ih0  = (const float*)d_in[3];
    const float* W_hh0  = (const float*)d_in[4];
    const float* b_ih0  = (const float*)d_in[5];
    const float* b_hh0  = (const float*)d_in[6];
    const float* W_ih1  = (const float*)d_in[7];
    const float* W_hh1  = (const float*)d_in[8];
    const float* b_ih1  = (const float*)d_in[9];
    const float* b_hh1  = (const float*)d_in[10];
    const float* W_out  = (const float*)d_in[11];
    const float* b_out  = (const float*)d_in[12];
    float* out = (float*)d_out;

    char* ws = (char*)d_ws;
    _Float16* x0p = (_Float16*)ws;                         // 32768*400*2 = 26,214,400 B
    float* h1s = (float*)(ws + 26214400);                  // 32768*100*4 = 13,107,200 B
    float* Wc  = (float*)(ws + 26214400 + 13107200);       // 400*300*4   =    480,000 B
    float* bc  = Wc + 120000;                              // 400*4 B

    k_precomp<<<471, 256, 0, stream>>>(W_inp, b_inp, W_ih0, b_ih0, b_hh0, Wc, bc);
    k_xproj<<<1024, 512, 0, stream>>>(inputs, Wc, bc, x0p);
    k_scan<<<1, 512, 0, stream>>>(x0p, W_hh0, W_ih1, W_hh1, b_ih1, b_hh1, h1s, out + OUT_BASE);
    k_out<<<1024, 320, 0, stream>>>(h1s, W_out, b_out, out);
}